// Round 3
// baseline (917.499 us; speedup 1.0000x reference)
//
#include <hip/hip_runtime.h>

#define EPS 1e-5f

typedef __attribute__((ext_vector_type(8))) short short8;
typedef __attribute__((ext_vector_type(4))) float float4v;

__device__ __forceinline__ unsigned short f2bf(float x) {
  unsigned int u = __builtin_bit_cast(unsigned int, x);
  u += 0x7fffu + ((u >> 16) & 1u);   // RNE to bf16
  return (unsigned short)(u >> 16);
}

// ---------------- Kernel 1: LayerNorm ----------------
__global__ __launch_bounds__(256) void ln_kernel(
    const float* __restrict__ x, const float* __restrict__ gamma,
    const float* __restrict__ beta, float* __restrict__ xn) {
  const int row = blockIdx.x * 4 + (threadIdx.x >> 6);
  const int lane = threadIdx.x & 63;
  const float2 v = ((const float2*)(x + (size_t)row * 128))[lane];
  float s = v.x + v.y;
#pragma unroll
  for (int off = 1; off < 64; off <<= 1) s += __shfl_xor(s, off);
  const float mu = s * (1.f / 128.f);
  const float dx = v.x - mu, dy = v.y - mu;
  float qv = dx * dx + dy * dy;
#pragma unroll
  for (int off = 1; off < 64; off <<= 1) qv += __shfl_xor(qv, off);
  const float rstd = 1.f / sqrtf(qv * (1.f / 128.f) + EPS);
  const float2 g = ((const float2*)gamma)[lane];
  const float2 be = ((const float2*)beta)[lane];
  float2 o;
  o.x = dx * rstd * g.x + be.x;
  o.y = dy * rstd * g.y + be.y;
  ((float2*)(xn + (size_t)row * 128))[lane] = o;
}

// ---------------- Kernel 2: qk = xn @ Wqk  [4160,128]x[128,512] ----------------
__global__ __launch_bounds__(256) void qk_kernel(
    const float* __restrict__ xn, const float* __restrict__ Wqk,
    float* __restrict__ qk) {
  __shared__ float xsx[32][130];
  __shared__ float wsx[128][68];
  const int t = threadIdx.x;
  const int r0 = blockIdx.x * 32, c0 = blockIdx.y * 64;
  for (int i = t; i < 32 * 32; i += 256) {
    int r = i >> 5, c = (i & 31) << 2;
    float4 v = *(const float4*)(xn + (size_t)(r0 + r) * 128 + c);
    float* dst = &xsx[r][c];
    dst[0] = v.x; dst[1] = v.y; dst[2] = v.z; dst[3] = v.w;
  }
  for (int i = t; i < 128 * 16; i += 256) {
    int k = i >> 4, c = (i & 15) << 2;
    *(float4*)&wsx[k][c] = *(const float4*)(Wqk + (size_t)k * 512 + c0 + c);
  }
  __syncthreads();
  const int rr = (t >> 4) * 2, cc = (t & 15) * 4;
  float acc[2][4] = {{0.f, 0.f, 0.f, 0.f}, {0.f, 0.f, 0.f, 0.f}};
  for (int k = 0; k < 128; k++) {
    float4 wv4 = *(const float4*)&wsx[k][cc];
    float x0 = xsx[rr][k], x1 = xsx[rr + 1][k];
    acc[0][0] += x0 * wv4.x; acc[0][1] += x0 * wv4.y;
    acc[0][2] += x0 * wv4.z; acc[0][3] += x0 * wv4.w;
    acc[1][0] += x1 * wv4.x; acc[1][1] += x1 * wv4.y;
    acc[1][2] += x1 * wv4.z; acc[1][3] += x1 * wv4.w;
  }
#pragma unroll
  for (int r = 0; r < 2; r++) {
    float4 o;
    o.x = acc[r][0]; o.y = acc[r][1]; o.z = acc[r][2]; o.w = acc[r][3];
    *(float4*)(qk + (size_t)(r0 + rr + r) * 512 + c0 + cc) = o;
  }
}

// ---------------- Kernel 3: dots + softmax ----------------
// grid 512 = (b,h); writes attnT[h][n][m][b] fp32 (b-contiguous so attnv can
// read per-lane float4 along b)
__global__ __launch_bounds__(256) void softmax_kernel(
    const float* __restrict__ qk, float* __restrict__ attnT) {
  const int b = blockIdx.x >> 3, h = blockIdx.x & 7;
  __shared__ float qs[65][33];
  __shared__ float ks[65][33];
  __shared__ float dotsS[65][66];
  __shared__ float rsum[65];
  const int t = threadIdx.x;
  for (int i = t; i < 65 * 32; i += 256) {
    int n = i >> 5, d = i & 31;
    size_t base = ((size_t)b * 65 + n) * 512 + h * 32 + d;
    qs[n][d] = qk[base];
    ks[n][d] = qk[base + 256];
  }
  __syncthreads();
  const float scale = 0.17677669529663687f;  // 1/sqrt(32)
  for (int i = t; i < 65 * 65; i += 256) {
    int n = i / 65, mm = i - n * 65;
    float s = 0.f;
#pragma unroll
    for (int d = 0; d < 32; d++) s += qs[n][d] * ks[mm][d];
    dotsS[n][mm] = s * scale;
  }
  __syncthreads();
  if (t < 65) {
    float mx = -1e30f;
    for (int mm = 0; mm < 65; mm++) mx = fmaxf(mx, dotsS[t][mm]);
    float sum = 0.f;
    for (int mm = 0; mm < 65; mm++) {
      float e = __expf(dotsS[t][mm] - mx);
      dotsS[t][mm] = e;
      sum += e;
    }
    rsum[t] = 1.f / sum;
  }
  __syncthreads();
  for (int i = t; i < 65 * 65; i += 256) {
    int n = i / 65, mm = i - n * 65;
    attnT[(((size_t)h * 65 + n) * 65 + mm) * 64 + b] = dotsS[n][mm] * rsum[n];
  }
}

// ---------------- Kernel 4: the big contraction ----------------
// innerp[c][b,nq,e] = sum_{m in chunk c} attn[b,e>>5,nq,m] *
//                     sum_d xn[b,nq,d]*Wv[nq,m,d,e]
// grid 260 = (nq, mchunk); 512 threads; block covers ALL 256 e-cols so every
// Wv stage is a contiguous 64 KB global window (DRAM-stream friendly).
// Stage = d-half [64 d][256 e] -> bf16 LDS [256 e][64 k] XOR-swizzled,
// double-buffered (64 KB LDS). Column-per-thread global loads give the
// transpose for free while each wave instruction still reads 256 B contiguous.
__global__ __launch_bounds__(512, 4) void attnv_kernel(
    const float* __restrict__ xn, const float* __restrict__ attnT,
    const float* __restrict__ Wv, float* __restrict__ innerp) {
  __shared__ __align__(16) unsigned short buf[2][16384];  // [256 e][64 k] bf16

  const int nq = blockIdx.x >> 2;
  const int c = blockIdx.x & 3;
  const int m0 = c ? (c * 16 + 1) : 0;
  const int mlen = c ? 16 : 17;

  const int t = threadIdx.x;
  const int w = t >> 6, lane = t & 63;
  // staging role: column e_col, d-group dg (32 consecutive d)
  const int e_col = (w & 3) * 64 + lane;
  const int dg = w >> 2;
  // mfma role: batch-tile bt (16 rows), e-half eh (8 e-tiles)
  const int bt = w >> 1, eh = w & 1;
  const int er = lane & 15, q = lane >> 4;

  const float* wtile = Wv + ((size_t)nq * 65 + m0) * 32768 + (size_t)dg * 8192 + e_col;
  // stage (mrel, s): + mrel*32768 + s*16384, element i at + i*256

  float stg[32];
  // prologue: loads for step 0 (mrel=0, s=0)
#pragma unroll
  for (int i = 0; i < 32; i++) stg[i] = wtile[(size_t)i * 256];

  // A fragments (bf16), held for the whole loop. afr[s*2+ks] covers
  // k = s*64 + ks*32 + q*8 .. +7
  short8 afr[4];
  {
    const float* arow = xn + ((size_t)(bt * 16 + er) * 65 + nq) * 128;
#pragma unroll
    for (int idx = 0; idx < 4; idx++) {
      float4 v0 = *(const float4*)(arow + idx * 32 + q * 8);
      float4 v1 = *(const float4*)(arow + idx * 32 + q * 8 + 4);
      short8 a;
      a[0] = (short)f2bf(v0.x); a[1] = (short)f2bf(v0.y);
      a[2] = (short)f2bf(v0.z); a[3] = (short)f2bf(v0.w);
      a[4] = (short)f2bf(v1.x); a[5] = (short)f2bf(v1.y);
      a[6] = (short)f2bf(v1.z); a[7] = (short)f2bf(v1.w);
      afr[idx] = a;
    }
  }

  // attn values for this lane's 4 rows x 4 heads (heads eh*4..eh*4+3)
  float4 av4[4];
#define LOAD_AV(m)                                                            \
  {                                                                           \
    _Pragma("unroll")                                                         \
    for (int hg = 0; hg < 4; hg++) {                                          \
      size_t off = ((size_t)((eh * 4 + hg) * 65 + nq) * 65 + (m)) * 64 +      \
                   bt * 16 + q * 4;                                           \
      av4[hg] = *(const float4*)(attnT + off);                                \
    }                                                                         \
  }
  LOAD_AV(m0);

  // convert + swizzled write of stg into buffer b.
  // elem (e,k): chunk ch=k>>3 at slot (ch ^ (e&7)), i.e. byte e*128+slot*16
#define WRITE_BUF(bsel)                                                       \
  {                                                                           \
    unsigned short* dst = buf[bsel] + e_col * 64;                             \
    _Pragma("unroll")                                                         \
    for (int cj = 0; cj < 4; cj++) {                                          \
      int ch = dg * 4 + cj;                                                   \
      int slot = ch ^ (e_col & 7);                                            \
      short8 pk;                                                              \
      _Pragma("unroll")                                                       \
      for (int j = 0; j < 8; j++) pk[j] = (short)f2bf(stg[cj * 8 + j]);       \
      *(short8*)(dst + slot * 8) = pk;                                        \
    }                                                                         \
  }
  WRITE_BUF(0);
  // issue loads for step 1 (mrel=0, s=1)
#pragma unroll
  for (int i = 0; i < 32; i++) stg[i] = wtile[16384 + (size_t)i * 256];
  __syncthreads();

  float4v acc[8];
#pragma unroll
  for (int el = 0; el < 8; el++) acc[el] = (float4v){0.f, 0.f, 0.f, 0.f};

  const int S = 2 * mlen;
  for (int step = 0; step < S; step++) {
    const int cur = step & 1;       // buffer parity == stage parity
    const unsigned short* bb = buf[cur];
    const short8 a0 = afr[(step & 1) * 2], a1 = afr[(step & 1) * 2 + 1];
#pragma unroll
    for (int el = 0; el < 8; el++) {
      const unsigned short* rp = bb + ((eh * 8 + el) * 16 + er) * 64;
      float4v P = {0.f, 0.f, 0.f, 0.f};
      short8 B0 = *(const short8*)(rp + ((q ^ (er & 7)) << 3));
      short8 B1 = *(const short8*)(rp + (((4 + q) ^ (er & 7)) << 3));
      P = __builtin_amdgcn_mfma_f32_16x16x32_bf16(a0, B0, P, 0, 0, 0);
      P = __builtin_amdgcn_mfma_f32_16x16x32_bf16(a1, B1, P, 0, 0, 0);
      const float4 av = av4[el >> 1];
      acc[el][0] += av.x * P[0];
      acc[el][1] += av.y * P[1];
      acc[el][2] += av.z * P[2];
      acc[el][3] += av.w * P[3];
    }
    if (step + 1 < S) {
      WRITE_BUF(1 - cur);  // waits on stg loads (step+1 data), fills other buf
      if (step + 2 < S) {
        const int ns = step + 2;
        const float* p = wtile + (size_t)(ns >> 1) * 32768 + (size_t)(ns & 1) * 16384;
#pragma unroll
        for (int i = 0; i < 32; i++) stg[i] = p[(size_t)i * 256];
      }
      if ((step & 1) == 1) LOAD_AV(m0 + (step >> 1) + 1);
    }
    __syncthreads();
  }

  // epilogue: D layout col=lane&15 (e), row=(lane>>4)*4+r (batch)
  float* ip = innerp + (size_t)c * 1064960;
#pragma unroll
  for (int el = 0; el < 8; el++) {
#pragma unroll
    for (int r = 0; r < 4; r++) {
      int brow = bt * 16 + q * 4 + r;
      ip[((size_t)brow * 65 + nq) * 256 + (eh * 8 + el) * 16 + er] = acc[el][r];
    }
  }
}

// ---------------- Kernel 5: out = (sum of 4 inner partials) @ Wout + bout ----
__global__ __launch_bounds__(256) void outproj_kernel(
    const float* __restrict__ inner, const float* __restrict__ Wout,
    const float* __restrict__ bout, float* __restrict__ out) {
  __shared__ float isx[16][258];
  __shared__ float wsx[64][132];
  const int t = threadIdx.x;
  const int r0 = blockIdx.x * 16;
  for (int i = t; i < 16 * 64; i += 256) {
    int r = i >> 6, c = (i & 63) << 2;
    size_t off = (size_t)(r0 + r) * 256 + c;
    float4 v0 = *(const float4*)(inner + off);
    float4 v1 = *(const float4*)(inner + 1064960 + off);
    float4 v2 = *(const float4*)(inner + 2129920 + off);
    float4 v3 = *(const float4*)(inner + 3194880 + off);
    float* dst = &isx[r][c];
    dst[0] = v0.x + v1.x + v2.x + v3.x;
    dst[1] = v0.y + v1.y + v2.y + v3.y;
    dst[2] = v0.z + v1.z + v2.z + v3.z;
    dst[3] = v0.w + v1.w + v2.w + v3.w;
  }
  const int rr = (t >> 5) * 2, cc = (t & 31) * 4;
  float acc[2][4] = {{0.f, 0.f, 0.f, 0.f}, {0.f, 0.f, 0.f, 0.f}};
  for (int kc = 0; kc < 4; kc++) {
    __syncthreads();
    for (int i = t; i < 64 * 32; i += 256) {
      int k = i >> 5, c = (i & 31) << 2;
      *(float4*)&wsx[k][c] = *(const float4*)(Wout + (size_t)(kc * 64 + k) * 128 + c);
    }
    __syncthreads();
#pragma unroll 8
    for (int k = 0; k < 64; k++) {
      float4 wv4 = *(const float4*)&wsx[k][cc];
      float x0 = isx[rr][kc * 64 + k];
      float x1 = isx[rr + 1][kc * 64 + k];
      acc[0][0] += x0 * wv4.x; acc[0][1] += x0 * wv4.y;
      acc[0][2] += x0 * wv4.z; acc[0][3] += x0 * wv4.w;
      acc[1][0] += x1 * wv4.x; acc[1][1] += x1 * wv4.y;
      acc[1][2] += x1 * wv4.z; acc[1][3] += x1 * wv4.w;
    }
  }
  float4 bb = *(const float4*)(bout + cc);
#pragma unroll
  for (int r = 0; r < 2; r++) {
    float4 o;
    o.x = acc[r][0] + bb.x; o.y = acc[r][1] + bb.y;
    o.z = acc[r][2] + bb.z; o.w = acc[r][3] + bb.w;
    *(float4*)(out + (size_t)(r0 + rr + r) * 128 + cc) = o;
  }
}

extern "C" void kernel_launch(void* const* d_in, const int* in_sizes, int n_in,
                              void* d_out, int out_size, void* d_ws, size_t ws_size,
                              hipStream_t stream) {
  const float* x     = (const float*)d_in[0];
  const float* gamma = (const float*)d_in[1];
  const float* beta  = (const float*)d_in[2];
  const float* Wqk   = (const float*)d_in[3];
  const float* Wv    = (const float*)d_in[4];
  const float* Wout  = (const float*)d_in[5];
  const float* bout  = (const float*)d_in[6];
  float* out = (float*)d_out;
  float* ws  = (float*)d_ws;

  float* xn    = ws;                  //   532,480 f
  float* qk    = ws + 532480;         // 2,129,920 f
  float* attnT = ws + 2662400;        // 2,163,200 f  [h][n][m][b]
  float* inner = ws + 4825600;        // 4 x 1,064,960 f (m-chunk partials)

  ln_kernel<<<1040, 256, 0, stream>>>(x, gamma, beta, xn);
  qk_kernel<<<dim3(130, 8), 256, 0, stream>>>(xn, Wqk, qk);
  softmax_kernel<<<512, 256, 0, stream>>>(qk, attnT);
  attnv_kernel<<<260, 512, 0, stream>>>(xn, attnT, Wv, inner);
  outproj_kernel<<<260, 256, 0, stream>>>(inner, Wout, bout, out);
}